// Round 1
// baseline (66.454 us; speedup 1.0000x reference)
//
#include <hip/hip_runtime.h>
#include <cstddef>

// Problem constants (match reference)
constexpr int H_ = 320;
constexpr int W_ = 320;
constexpr int HW_ = H_ * W_;          // 102400
constexpr int NK = 440;               // offsets excluding center
constexpr int TILES = 25;             // tiles per k-plane; 102400/25 = 4096 elems/block
constexpr int SMOOTH_BLOCKS = NK * TILES;   // 11000
constexpr int DATA_BLOCKS = HW_ / 1024;     // 100 (256 thr * float4)
constexpr int TOTAL_BLOCKS = SMOOTH_BLOCKS + DATA_BLOCKS;

__device__ __forceinline__ int clampi(int v, int lo, int hi) {
    return v < lo ? lo : (v > hi ? hi : v);
}

__global__ __launch_bounds__(256) void bsl_partial_kernel(
    const float* __restrict__ img,   // output image [H,W]
    const float* __restrict__ tgt,   // target [H,W]
    const float* __restrict__ w,     // w_ij [440,H,W]
    float* __restrict__ partials)    // [TOTAL_BLOCKS]
{
    const int tid = threadIdx.x;
    float acc = 0.f;

    if (blockIdx.x < SMOOTH_BLOCKS) {
        // ---- smoothness term: one k-plane tile per block ----
        const int bk   = blockIdx.x / TILES;        // 0..439
        const int tile = blockIdx.x % TILES;        // 0..24
        // offset index skips the center (i=10,j=10) at flattened index 220
        const int idx = (bk < 220) ? bk : bk + 1;
        const int di  = idx / 21 - 10;
        const int dj  = idx - (idx / 21) * 21 - 10;
        const float* __restrict__ wp = w + (size_t)bk * HW_;
        const int base = tile * 4096;

#pragma unroll
        for (int it = 0; it < 4; ++it) {
            const int pos = base + it * 1024 + tid * 4;   // 16B aligned
            const int y = pos / W_;
            const int x = pos - y * W_;                   // 0..316, mult of 4

            const float4 w4 = *reinterpret_cast<const float4*>(wp + pos);
            const float4 c4 = *reinterpret_cast<const float4*>(img + pos);

            int ny = clampi(y + di, 0, H_ - 1);
            const float* __restrict__ nrow = img + ny * W_;
            const int xs = x + dj;

            float n0, n1, n2, n3;
            if (xs >= 0 && xs + 4 <= W_) {
                n0 = nrow[xs];     n1 = nrow[xs + 1];
                n2 = nrow[xs + 2]; n3 = nrow[xs + 3];
            } else {
                n0 = nrow[clampi(xs,     0, W_ - 1)];
                n1 = nrow[clampi(xs + 1, 0, W_ - 1)];
                n2 = nrow[clampi(xs + 2, 0, W_ - 1)];
                n3 = nrow[clampi(xs + 3, 0, W_ - 1)];
            }
            const float d0 = c4.x - n0;
            const float d1 = c4.y - n1;
            const float d2 = c4.z - n2;
            const float d3 = c4.w - n3;
            acc += w4.x * d0 * d0;
            acc += w4.y * d1 * d1;
            acc += w4.z * d2 * d2;
            acc += w4.w * d3 * d3;
        }
    } else {
        // ---- data term: (img - tgt)^2 ----
        const int base = (blockIdx.x - SMOOTH_BLOCKS) * 1024 + tid * 4;
        const float4 o4 = *reinterpret_cast<const float4*>(img + base);
        const float4 t4 = *reinterpret_cast<const float4*>(tgt + base);
        const float d0 = o4.x - t4.x;
        const float d1 = o4.y - t4.y;
        const float d2 = o4.z - t4.z;
        const float d3 = o4.w - t4.w;
        acc = d0 * d0 + d1 * d1 + d2 * d2 + d3 * d3;
    }

    // wave (64-lane) butterfly reduce, then 4-wave LDS reduce
    for (int off = 32; off > 0; off >>= 1)
        acc += __shfl_down(acc, off, 64);
    __shared__ float wsum[4];
    const int wid = tid >> 6;
    const int lane = tid & 63;
    if (lane == 0) wsum[wid] = acc;
    __syncthreads();
    if (tid == 0)
        partials[blockIdx.x] = wsum[0] + wsum[1] + wsum[2] + wsum[3];
}

__global__ __launch_bounds__(256) void bsl_final_kernel(
    const float* __restrict__ partials, float* __restrict__ out)
{
    const int tid = threadIdx.x;
    double s = 0.0, d = 0.0;
    for (int i = tid; i < SMOOTH_BLOCKS; i += 256) s += (double)partials[i];
    for (int i = SMOOTH_BLOCKS + tid; i < TOTAL_BLOCKS; i += 256) d += (double)partials[i];

    __shared__ double sm[256];
    __shared__ double sd[256];
    sm[tid] = s; sd[tid] = d;
    __syncthreads();
    for (int st = 128; st > 0; st >>= 1) {
        if (tid < st) { sm[tid] += sm[tid + st]; sd[tid] += sd[tid + st]; }
        __syncthreads();
    }
    if (tid == 0) {
        // H*W*LAM*mean(w d^2) = LAM * S / 440 ;  data = D / (H*W)
        out[0] = (float)(128.0 * sm[0] / 440.0 + sd[0] / (double)HW_);
    }
}

extern "C" void kernel_launch(void* const* d_in, const int* in_sizes, int n_in,
                              void* d_out, int out_size, void* d_ws, size_t ws_size,
                              hipStream_t stream) {
    const float* img = (const float*)d_in[0];   // output [320,320]
    const float* tgt = (const float*)d_in[1];   // target [320,320]
    const float* wij = (const float*)d_in[2];   // w_ij [440,320,320]
    float* out = (float*)d_out;
    float* partials = (float*)d_ws;             // TOTAL_BLOCKS floats = 44.4 KB

    bsl_partial_kernel<<<TOTAL_BLOCKS, 256, 0, stream>>>(img, tgt, wij, partials);
    bsl_final_kernel<<<1, 256, 0, stream>>>(partials, out);
}

// Round 2
// 37.884 us; speedup vs baseline: 1.7542x; 1.7542x over previous
//
#include <hip/hip_runtime.h>
#include <cstddef>

// Problem constants (match reference)
constexpr int H_ = 320;
constexpr int W_ = 320;
constexpr int HW_ = H_ * W_;            // 102400
constexpr int NK = 440;                 // offsets excluding center
constexpr int TS = 32;                  // spatial tile edge
constexpr int TPR = W_ / TS;            // 10 tiles per row
constexpr int NTILES = TPR * TPR;       // 100
constexpr int KC = 20;                  // k-offsets per chunk
constexpr int NKC = NK / KC;            // 22 chunks
constexpr int SMOOTH_BLOCKS = NTILES * NKC;   // 2200
constexpr int NPART = SMOOTH_BLOCKS + NTILES; // 2300 partials
constexpr int HALO = 10;
constexpr int LW = TS + 2 * HALO;       // 52
constexpr int LSTRIDE = LW + 1;         // 53 (odd -> worst LDS conflict 2-way = free)

__device__ __forceinline__ int clampi(int v, int lo, int hi) {
    return v < lo ? lo : (v > hi ? hi : v);
}

// full-block reduce; rbuf is 4 floats of shared mem. Safe to call twice
// (leading barrier protects rbuf reuse). Result valid on tid==0 only.
__device__ __forceinline__ float block_reduce(float v, float* rbuf, int tid) {
    __syncthreads();
    for (int off = 32; off > 0; off >>= 1)
        v += __shfl_down(v, off, 64);
    if ((tid & 63) == 0) rbuf[tid >> 6] = v;
    __syncthreads();
    return rbuf[0] + rbuf[1] + rbuf[2] + rbuf[3];
}

__global__ __launch_bounds__(256) void bsl_main_kernel(
    const float* __restrict__ img,   // [H,W]
    const float* __restrict__ tgt,   // [H,W]
    const float* __restrict__ w,     // [440,H,W]
    float* __restrict__ partials)    // [NPART]
{
    __shared__ float lds[LW * LSTRIDE];   // 52*53*4 = 11 KB
    __shared__ float rbuf[4];
    const int tid = threadIdx.x;

    const int tileId = blockIdx.x / NKC;
    const int kc     = blockIdx.x % NKC;
    const int ty = tileId / TPR, tx = tileId % TPR;
    const int y0 = ty * TS, x0 = tx * TS;

    // ---- stage img tile + halo into LDS (replicate padding via clamp) ----
    for (int e = tid; e < LW * LW; e += 256) {
        const int ly = e / LW, lx = e - ly * LW;
        const int gy = clampi(y0 - HALO + ly, 0, H_ - 1);
        const int gx = clampi(x0 - HALO + lx, 0, W_ - 1);
        lds[ly * LSTRIDE + lx] = img[gy * W_ + gx];
    }
    __syncthreads();

    // thread -> 4 consecutive pixels of the 32x32 tile
    const int row = tid >> 3;            // 0..31
    const int c4  = (tid & 7) * 4;       // 0,4,...,28
    const int cbase = (HALO + row) * LSTRIDE + HALO + c4;
    const float c0 = lds[cbase + 0];
    const float c1 = lds[cbase + 1];
    const float c2 = lds[cbase + 2];
    const float c3 = lds[cbase + 3];

    // ---- stream KC w-plane tiles against the LDS image ----
    float acc = 0.f;
    const float* wp = w + (size_t)(kc * KC) * HW_ + (y0 + row) * W_ + x0 + c4;
#pragma unroll 4
    for (int kk = 0; kk < KC; ++kk) {
        const int bk  = kc * KC + kk;                 // w-plane index (center skipped)
        const int idx = (bk < 220) ? bk : bk + 1;     // re-insert center gap
        const int q   = idx / 21;
        const int di  = q - 10;
        const int dj  = idx - q * 21 - 10;

        const float4 w4 = *reinterpret_cast<const float4*>(wp);
        wp += HW_;

        const int nb = cbase + di * LSTRIDE + dj;     // wave-uniform offset add
        const float n0 = lds[nb + 0];
        const float n1 = lds[nb + 1];
        const float n2 = lds[nb + 2];
        const float n3 = lds[nb + 3];
        const float d0 = c0 - n0, d1 = c1 - n1, d2 = c2 - n2, d3 = c3 - n3;
        acc += w4.x * d0 * d0;
        acc += w4.y * d1 * d1;
        acc += w4.z * d2 * d2;
        acc += w4.w * d3 * d3;
    }

    const float ssum = block_reduce(acc, rbuf, tid);
    if (tid == 0) partials[blockIdx.x] = ssum;

    // ---- data term: once per tile (kc==0 blocks) ----
    if (kc == 0) {
        const float4 t4 = *reinterpret_cast<const float4*>(
            tgt + (y0 + row) * W_ + x0 + c4);
        const float d0 = c0 - t4.x, d1 = c1 - t4.y;
        const float d2 = c2 - t4.z, d3 = c3 - t4.w;
        const float dsum = block_reduce(d0*d0 + d1*d1 + d2*d2 + d3*d3, rbuf, tid);
        if (tid == 0) partials[SMOOTH_BLOCKS + tileId] = dsum;
    }
}

__global__ __launch_bounds__(256) void bsl_final_kernel(
    const float* __restrict__ partials, float* __restrict__ out)
{
    const int tid = threadIdx.x;
    double s = 0.0, d = 0.0;
    for (int i = tid; i < SMOOTH_BLOCKS; i += 256) s += (double)partials[i];
    for (int i = SMOOTH_BLOCKS + tid; i < NPART; i += 256) d += (double)partials[i];

    __shared__ double sm[256];
    __shared__ double sd[256];
    sm[tid] = s; sd[tid] = d;
    __syncthreads();
    for (int st = 128; st > 0; st >>= 1) {
        if (tid < st) { sm[tid] += sm[tid + st]; sd[tid] += sd[tid + st]; }
        __syncthreads();
    }
    if (tid == 0) {
        // H*W*LAM*mean(w d^2) = LAM * S / 440 ; data = D / (H*W)
        out[0] = (float)(128.0 * sm[0] / 440.0 + sd[0] / (double)HW_);
    }
}

extern "C" void kernel_launch(void* const* d_in, const int* in_sizes, int n_in,
                              void* d_out, int out_size, void* d_ws, size_t ws_size,
                              hipStream_t stream) {
    const float* img = (const float*)d_in[0];   // output [320,320]
    const float* tgt = (const float*)d_in[1];   // target [320,320]
    const float* wij = (const float*)d_in[2];   // w_ij [440,320,320]
    float* out = (float*)d_out;
    float* partials = (float*)d_ws;             // NPART floats = 9.2 KB

    bsl_main_kernel<<<SMOOTH_BLOCKS, 256, 0, stream>>>(img, tgt, wij, partials);
    bsl_final_kernel<<<1, 256, 0, stream>>>(partials, out);
}